// Round 2
// baseline (98.495 us; speedup 1.0000x reference)
//
#include <hip/hip_runtime.h>
#include <math.h>

// DecisionTrees2: out[n, idx] = prod_f softmax((x[n,f]*W + b[f]) / 0.1)[d_f]
// idx = d0*4^7 + ... + d7.  Factor as Phi[hi] * Plo[lo], hi/lo = 4 digits each.
// One block per row; 512 MiB f32 output => HBM-write bound.

__global__ __launch_bounds__(256) void dt2_kernel(const float* __restrict__ x,
                                                  const float* __restrict__ cps,
                                                  float* __restrict__ out) {
    __shared__ float bins[8][4];
    __shared__ float Phi[256];
    __shared__ float Plo[256];

    const int n = blockIdx.x;
    const int t = threadIdx.x;

    // --- per-row bin softmaxes (threads 0..7, one feature each) ---
    if (t < 8) {
        const int f = t;
        const float a = cps[f * 3 + 0];
        const float b = cps[f * 3 + 1];
        const float c = cps[f * 3 + 2];
        // sort 3 values
        const float lo = fminf(a, b), hi = fmaxf(a, b);
        const float c0 = fminf(lo, c);
        const float c2 = fmaxf(hi, c);
        const float c1 = fmaxf(lo, fminf(hi, c));
        // bias = cumsum of [0, -c0, -c1, -c2]
        const float b0 = 0.0f;
        const float b1 = -c0;
        const float b2 = b1 - c1;
        const float b3 = b2 - c2;
        const float xv = x[n * 8 + f];
        // h = x*W + b, W = [1,2,3,4]
        const float h0 = xv * 1.0f + b0;
        const float h1 = xv * 2.0f + b1;
        const float h2 = xv * 3.0f + b2;
        const float h3 = xv * 4.0f + b3;
        const float m = fmaxf(fmaxf(h0, h1), fmaxf(h2, h3));
        // softmax(h / 0.1) with max subtraction
        const float e0 = __expf((h0 - m) * 10.0f);
        const float e1 = __expf((h1 - m) * 10.0f);
        const float e2 = __expf((h2 - m) * 10.0f);
        const float e3 = __expf((h3 - m) * 10.0f);
        const float inv = 1.0f / (e0 + e1 + e2 + e3);
        bins[f][0] = e0 * inv;
        bins[f][1] = e1 * inv;
        bins[f][2] = e2 * inv;
        bins[f][3] = e3 * inv;
    }
    __syncthreads();

    // --- partial products: Phi over features 0..3, Plo over 4..7 ---
    {
        const int d0 = (t >> 6) & 3;
        const int d1 = (t >> 4) & 3;
        const int d2 = (t >> 2) & 3;
        const int d3 = t & 3;
        Phi[t] = bins[0][d0] * bins[1][d1] * bins[2][d2] * bins[3][d3];
        Plo[t] = bins[4][d0] * bins[5][d1] * bins[6][d2] * bins[7][d3];
    }
    __syncthreads();

    // --- write 65536 floats = 16384 float4, coalesced ---
    float4* out4 = (float4*)(out + (size_t)n * 65536);
    #pragma unroll 8
    for (int j = t; j < 16384; j += 256) {
        const float ph = Phi[j >> 6];
        const int l4 = (j & 63) << 2;
        float4 v;
        v.x = ph * Plo[l4 + 0];
        v.y = ph * Plo[l4 + 1];
        v.z = ph * Plo[l4 + 2];
        v.w = ph * Plo[l4 + 3];
        out4[j] = v;
    }
}

extern "C" void kernel_launch(void* const* d_in, const int* in_sizes, int n_in,
                              void* d_out, int out_size, void* d_ws, size_t ws_size,
                              hipStream_t stream) {
    const float* x   = (const float*)d_in[0];
    const float* cps = (const float*)d_in[1];
    float* out = (float*)d_out;
    const int N = in_sizes[0] / 8;  // 2048
    dt2_kernel<<<N, 256, 0, stream>>>(x, cps, out);
}